// Round 10
// baseline (1046.182 us; speedup 1.0000x reference)
//
#include <hip/hip_runtime.h>
#include <stdint.h>

typedef __bf16 bfv8 __attribute__((ext_vector_type(8)));
typedef short s16x8 __attribute__((ext_vector_type(8)));
typedef short s16x4 __attribute__((ext_vector_type(4)));
typedef float f32x4 __attribute__((ext_vector_type(4)));
typedef float f32x16 __attribute__((ext_vector_type(16)));

#define MFMA(a, b, c) __builtin_amdgcn_mfma_f32_16x16x32_bf16(a, b, c, 0, 0, 0)
#define MFMA32(a, b, c) __builtin_amdgcn_mfma_f32_32x32x16_bf16(a, b, c, 0, 0, 0)

__device__ __forceinline__ short f2bf(float f) {
  union { float f; unsigned u; } v; v.f = f;
  unsigned r = v.u + 0x7FFFu + ((v.u >> 16) & 1u);
  return (short)(r >> 16);
}
__device__ __forceinline__ float bf2f(short s) {
  union { unsigned u; float f; } v; v.u = ((unsigned)(unsigned short)s) << 16;
  return v.f;
}
__device__ __forceinline__ unsigned pack2(float a, float b) {
  return (unsigned)(unsigned short)f2bf(a) | ((unsigned)(unsigned short)f2bf(b) << 16);
}
__device__ __forceinline__ bfv8 mkfrag(unsigned a, unsigned b, unsigned c, unsigned d) {
  union { unsigned u[4]; bfv8 v; } t; t.u[0] = a; t.u[1] = b; t.u[2] = c; t.u[3] = d;
  return t.v;
}

// async global->LDS, 16B per lane; lds base must be wave-uniform
__device__ __forceinline__ void async_cp16(const short* g, short* l) {
  auto gp = reinterpret_cast<const uint32_t __attribute__((address_space(1)))*>(
      reinterpret_cast<uintptr_t>(g));
  auto lp = reinterpret_cast<uint32_t __attribute__((address_space(3)))*>(
      reinterpret_cast<uintptr_t>(l));
  __builtin_amdgcn_global_load_lds(gp, lp, 16, 0, 0);
}

// ------------------------------------------------------------- convert pass
__global__ __launch_bounds__(256) void convert_all(
    const float* __restrict__ x, const float* __restrict__ qkvw,
    const float* __restrict__ projw, const float* __restrict__ rph,
    const float* __restrict__ rpw, short* __restrict__ Xbf,
    short* __restrict__ Wq, short* __restrict__ Wp, short* __restrict__ Rhb,
    short* __restrict__ Rwb) {
  const int NX = 9633792;   // 50176*192
  const int NW1 = 442368;   // 2304*768/4
  const int NW2 = 147456;   // 768*768/4
  const int NR = 512;       // 32*16
  int idx = blockIdx.x * 256 + threadIdx.x;
  if (idx < NX) {
    int t = idx / 192, cq = idx - t * 192;
    int wdx = t / 196, n = t - wdx * 196;
    int b = wdx >> 4, wl = wdx & 15;
    int nh = n / 14;
    int hh = (wl >> 2) * 14 + nh;
    int ww = (wl & 3) * 14 + (n - nh * 14);
    float4 v = *(const float4*)(x + ((b * 56 + hh) * 56 + ww) * 768 + cq * 4);
    s16x4 s = {f2bf(v.x), f2bf(v.y), f2bf(v.z), f2bf(v.w)};
    *(s16x4*)(Xbf + idx * 4) = s;
  } else if (idx < NX + NW1) {
    int i = idx - NX;
    float4 v = ((const float4*)qkvw)[i];
    s16x4 s = {f2bf(v.x), f2bf(v.y), f2bf(v.z), f2bf(v.w)};
    *(s16x4*)(Wq + i * 4) = s;
  } else if (idx < NX + NW1 + NW2) {
    int i = idx - NX - NW1;
    float4 v = ((const float4*)projw)[i];
    s16x4 s = {f2bf(v.x), f2bf(v.y), f2bf(v.z), f2bf(v.w)};
    *(s16x4*)(Wp + i * 4) = s;
  } else if (idx < NX + NW1 + NW2 + 2 * NR) {
    int i = idx - NX - NW1 - NW2;
    int which = i >> 9;
    int j = i & 511;
    int p = j >> 4, q = j & 15;
    const float* src = which ? rpw : rph;
    short* dst = which ? Rwb : Rhb;
    s16x4 s = {0, 0, 0, 0};
    if (p < 27) {
      float4 v = *(const float4*)(src + p * 64 + q * 4);
      s = (s16x4){f2bf(v.x), f2bf(v.y), f2bf(v.z), f2bf(v.w)};
    }
    *(s16x4*)(dst + p * 64 + q * 4) = s;
  }
}

// ============================================================= 256^2 GEMMs
// R4 structure (verified 215.7us qkv): BM=BN=256, BK=64, 512 thr (8 waves
// 2x4), per-wave 128x64 out. LDS 2 bufs x (A+B) = 128 KB. Stage(t+1) issued
// before COMPUTE(t); vmcnt(0)+raw barrier per half-tile. Swizzle: source
// chunk ss = ls^lr pre-swizzle, linear LDS; read slot = (kh*4+g)^(li&7)
// -> 2-way conflicts only (free).

#define GEMM_PRE()                                                            \
  const int tid = threadIdx.x, lane = tid & 63, w = tid >> 6;                 \
  const int wr = w >> 2, wc = w & 3;                                          \
  const int li = lane & 15, g = lane >> 4;                                    \
  const int lr = lane >> 3, ls = lane & 7;                                    \
  const int ss = ls ^ lr;                                                     \
  f32x4 acc[8][4];                                                            \
  _Pragma("unroll") for (int i = 0; i < 8; ++i)                               \
  _Pragma("unroll") for (int j = 0; j < 4; ++j)                               \
      acc[i][j] = (f32x4){0.f, 0.f, 0.f, 0.f};

#define GEMM_STAGE(buf, t)                                                    \
  {                                                                           \
    _Pragma("unroll") for (int q = 0; q < 4; ++q) {                           \
      async_cp16(Asrc + q * 8 * 768 + (t) * 64, &As[buf][(w * 32 + q * 8) * 64]); \
      async_cp16(Bsrc + q * 8 * 768 + (t) * 64, &Bs[buf][(w * 32 + q * 8) * 64]); \
    }                                                                         \
  }

#define GEMM_WAITBAR()                                                        \
  asm volatile("s_waitcnt vmcnt(0)" ::: "memory");                            \
  __builtin_amdgcn_sched_barrier(0);                                          \
  __builtin_amdgcn_s_barrier();

#define GEMM_COMPUTE(buf)                                                     \
  {                                                                           \
    const short* Ab = As[buf];                                                \
    const short* Bb = Bs[buf];                                                \
    bfv8 bfr[4][2];                                                           \
    _Pragma("unroll") for (int nf = 0; nf < 4; ++nf)                          \
    _Pragma("unroll") for (int kh = 0; kh < 2; ++kh)                          \
        bfr[nf][kh] = *(const bfv8*)&Bb[(wc * 64 + nf * 16 + li) * 64 +       \
                                        (((kh * 4 + g) ^ (li & 7)) * 8)];     \
    _Pragma("unroll") for (int mh = 0; mh < 2; ++mh) {                        \
      bfv8 af[4][2];                                                          \
      _Pragma("unroll") for (int mf = 0; mf < 4; ++mf)                        \
      _Pragma("unroll") for (int kh = 0; kh < 2; ++kh)                        \
          af[mf][kh] = *(const bfv8*)&Ab[(wr * 128 + mh * 64 + mf * 16 + li) * 64 + \
                                         (((kh * 4 + g) ^ (li & 7)) * 8)];    \
      __builtin_amdgcn_s_setprio(1);                                          \
      _Pragma("unroll") for (int mf = 0; mf < 4; ++mf)                        \
      _Pragma("unroll") for (int nf = 0; nf < 4; ++nf) {                      \
        acc[mh * 4 + mf][nf] = MFMA(af[mf][0], bfr[nf][0], acc[mh * 4 + mf][nf]); \
        acc[mh * 4 + mf][nf] = MFMA(af[mf][1], bfr[nf][1], acc[mh * 4 + mf][nf]); \
      }                                                                       \
      __builtin_amdgcn_s_setprio(0);                                          \
    }                                                                         \
  }

#define GEMM_LOOP()                                                           \
  GEMM_STAGE(0, 0);                                                           \
  _Pragma("unroll 1") for (int tt = 0; tt < 6; ++tt) {                        \
    GEMM_WAITBAR();                                                           \
    GEMM_STAGE(1, 2 * tt + 1);                                                \
    GEMM_COMPUTE(0);                                                          \
    GEMM_WAITBAR();                                                           \
    if (tt < 5) GEMM_STAGE(0, 2 * tt + 2);                                    \
    GEMM_COMPUTE(1);                                                          \
  }

// ------------------------------------------------------------- qkv gemm
__global__ __launch_bounds__(512, 2) void qkv_gemm(
    const short* __restrict__ Xbf, const short* __restrict__ Wq,
    const float* __restrict__ qkvb, short* __restrict__ Q,
    short* __restrict__ K, short* __restrict__ V) {
  __shared__ short As[2][256 * 64];
  __shared__ short Bs[2][256 * 64];
  // grid 1764 = 196 m-tiles x 9 n-tiles; bijective XCD swizzle (q=220, r=4)
  int bid = blockIdx.x;
  int xcd = bid & 7, pos = bid >> 3;
  int wgid = (xcd < 4) ? xcd * 221 + pos : 884 + (xcd - 4) * 220 + pos;
  int bm = wgid / 9, bn = wgid - bm * 9;

  GEMM_PRE();
  const short* Asrc = Xbf + (bm * 256 + w * 32 + lr) * 768 + ss * 8;
  const short* Bsrc = Wq + (bn * 256 + w * 32 + lr) * 768 + ss * 8;

  GEMM_LOOP();

  // epilogue: scatter into Q/K/V [window*head][196][64]
  short* dst = (bn < 3) ? Q : ((bn < 6) ? K : V);
  const int head = (bn % 3) * 4 + wc;
  float bias[4];
#pragma unroll
  for (int nf = 0; nf < 4; ++nf) bias[nf] = qkvb[bn * 256 + wc * 64 + nf * 16 + li];
#pragma unroll
  for (int mi = 0; mi < 8; ++mi) {
    int rbase = bm * 256 + wr * 128 + (mi >> 2) * 64 + (mi & 3) * 16 + g * 4;
#pragma unroll
    for (int j = 0; j < 4; ++j) {
      int trow = rbase + j;
      int wdx = trow / 196, n = trow - wdx * 196;
      int base = ((wdx * 12 + head) * 196 + n) * 64;
#pragma unroll
      for (int nf = 0; nf < 4; ++nf)
        dst[base + nf * 16 + li] = f2bf(acc[mi][nf][j] + bias[nf]);
    }
  }
}

// ------------------------------------------------------------- proj gemm
__global__ __launch_bounds__(512, 2) void proj_gemm(
    const short* __restrict__ AO, const short* __restrict__ Wp,
    const float* __restrict__ projb, float* __restrict__ out) {
  __shared__ short As[2][256 * 64];
  __shared__ short Bs[2][256 * 64];
  // grid 588 = 196 x 3; bijective XCD swizzle (q=73, r=4)
  int bid = blockIdx.x;
  int xcd = bid & 7, pos = bid >> 3;
  int wgid = (xcd < 4) ? xcd * 74 + pos : 296 + (xcd - 4) * 73 + pos;
  int bm = wgid / 3, bn = wgid - bm * 3;

  GEMM_PRE();
  const short* Asrc = AO + (bm * 256 + w * 32 + lr) * 768 + ss * 8;
  const short* Bsrc = Wp + (bn * 256 + w * 32 + lr) * 768 + ss * 8;

  GEMM_LOOP();

  // epilogue: window-unpartition scatter, f32 out
  float bias[4];
#pragma unroll
  for (int nf = 0; nf < 4; ++nf) bias[nf] = projb[bn * 256 + wc * 64 + nf * 16 + li];
  const int col0 = bn * 256 + wc * 64 + li;
#pragma unroll
  for (int mi = 0; mi < 8; ++mi) {
    int rbase = bm * 256 + wr * 128 + (mi >> 2) * 64 + (mi & 3) * 16 + g * 4;
#pragma unroll
    for (int j = 0; j < 4; ++j) {
      int trow = rbase + j;
      int wdx = trow / 196, n = trow - wdx * 196;
      int b = wdx >> 4, wl = wdx & 15;
      int nh = n / 14;
      int hh = (wl >> 2) * 14 + nh;
      int ww = (wl & 3) * 14 + (n - nh * 14);
      float* orow = out + ((b * 56 + hh) * 56 + ww) * 768 + col0;
#pragma unroll
      for (int nf = 0; nf < 4; ++nf)
        orow[nf * 16] = acc[mi][nf][j] + bias[nf];
    }
  }
}

// ------------------------------------------------------------- attention
// R10: 256 threads (4 waves) per block -> at VGPR ~180 (2 waves/SIMD) two
// blocks co-reside per CU (LDS 2x77.5KB=155 <= 160), so one block's global
// staging overlaps the other's compute. Each wave loops m-tiles {w, w+4}.
// Grid XCD-aligned to qkv's write map (32 windows per XCD) for L2 warmth.
__global__ __launch_bounds__(256, 2) void attn_kernel(
    const short* __restrict__ Q, const short* __restrict__ K,
    const short* __restrict__ V, const short* __restrict__ Rhb,
    const short* __restrict__ Rwb, short* __restrict__ AO) {
  __shared__ short Ks[196 * 64];    // K rows, 16B-chunk XOR swizzle
  __shared__ short Vt[64 * 204];    // V^T [d][k], k 0..203 (196.. zeroed)
  __shared__ short relh[224 * 28];  // relall_h[q][p]
  __shared__ short relw[224 * 28];
  __shared__ short2 hw[224];        // (13-hk, 13-wk) per k

  const int bid = blockIdx.x;
  const int bh = (bid & 7) * 384 + (bid >> 3);  // 3072 = 8*384, bijective
  const int wdx = bh / 12, head = bh - wdx * 12;
  const int tid = threadIdx.x, lane = tid & 63, wave = tid >> 6;  // 0..3
  const int l31 = lane & 31, hb = lane >> 5;
  const short* Qb = Q + bh * 12544;
  const short* Kb = K + bh * 12544;
  const short* Vb = V + bh * 12544;

  // ---- staging (4 waves, 256 thr) ----
  if (tid < 64) {
    s16x8 z = {0, 0, 0, 0, 0, 0, 0, 0};
    *(s16x8*)&Vt[tid * 204 + 196] = z;
  }
  for (int c = tid; c < 1568; c += 256) {
    int r = c >> 3, cc = c & 7;
    s16x8 v = *(const s16x8*)(Kb + r * 64 + cc * 8);
    *(s16x8*)&Ks[r * 64 + (((cc ^ (r & 7))) << 3)] = v;
  }
  for (int t = tid; t < 784; t += 256) {
    int dseg = t / 98, kp = t - dseg * 98, d0 = dseg * 8;
    s16x8 a = *(const s16x8*)(Vb + (2 * kp) * 64 + d0);
    s16x8 b = *(const s16x8*)(Vb + (2 * kp + 1) * 64 + d0);
#pragma unroll
    for (int i = 0; i < 8; ++i)
      *(short2*)&Vt[(d0 + i) * 204 + 2 * kp] = make_short2(a[i], b[i]);
  }
  if (tid < 224) {
    int kc = (tid > 195) ? 195 : tid;
    int hk = kc / 14, wk = kc - hk * 14;
    hw[tid] = make_short2((short)(13 - hk), (short)(13 - wk));
  }
  __syncthreads();

  // ---- per-m-tile pipeline; wave w handles mt = w and w+4 ----
  for (int mt = wave; mt < 7; mt += 4) {
    const int m0 = mt * 32;
    const int qv = (m0 + l31 > 195) ? 195 : m0 + l31;

    // Q fragments + rel mini-GEMMs (B-frags straight from global tables)
    bfv8 qf[4];
    {
      f32x16 ra = {0.f, 0.f, 0.f, 0.f, 0.f, 0.f, 0.f, 0.f,
                   0.f, 0.f, 0.f, 0.f, 0.f, 0.f, 0.f, 0.f};
      f32x16 rw_ = ra;
#pragma unroll
      for (int s = 0; s < 4; ++s) {
        qf[s] = *(const bfv8*)(Qb + qv * 64 + s * 16 + hb * 8);
        ra = MFMA32(*(const bfv8*)(Rhb + l31 * 64 + s * 16 + hb * 8), qf[s], ra);
        rw_ = MFMA32(*(const bfv8*)(Rwb + l31 * 64 + s * 16 + hb * 8), qf[s], rw_);
      }
#pragma unroll
      for (int reg = 0; reg < 16; ++reg) {
        int p = (reg & 3) + 8 * (reg >> 2) + 4 * hb;
        if (!(hb && reg >= 12)) {  // p < 28
          relh[(m0 + l31) * 28 + p] = f2bf(ra[reg]);
          relw[(m0 + l31) * 28 + p] = f2bf(rw_[reg]);
        }
      }
      // same-wave LDS write->read (in-order per wave): no barrier needed
    }

    const int hq = qv / 14;
    const int wq = qv - hq * 14;
    const short* relhq = &relh[qv * 28 + hq];
    const short* relwq = &relw[qv * 28 + wq];

    f32x16 oacc0 = {0.f, 0.f, 0.f, 0.f, 0.f, 0.f, 0.f, 0.f,
                    0.f, 0.f, 0.f, 0.f, 0.f, 0.f, 0.f, 0.f};
    f32x16 oacc1 = oacc0;
    float psum = 0.f;

#pragma unroll
    for (int nt = 0; nt < 7; ++nt) {
      int krow = nt * 32 + l31;
      int krc = (krow > 195) ? 195 : krow;
      const int rb = krc * 64, rx = krc & 7;
      f32x16 st = {0.f, 0.f, 0.f, 0.f, 0.f, 0.f, 0.f, 0.f,
                   0.f, 0.f, 0.f, 0.f, 0.f, 0.f, 0.f, 0.f};
#pragma unroll
      for (int s = 0; s < 4; ++s) {
        bfv8 kf = *(const bfv8*)&Ks[rb + (((2 * s + hb) ^ rx) << 3)];
        st = MFMA32(kf, qf[s], st);
      }
      float pv[16];
      float lsum = 0.f;
#pragma unroll
      for (int reg = 0; reg < 16; ++reg) {
        int koff = (reg & 3) + 8 * (reg >> 2) + 4 * hb;
        int k = nt * 32 + koff;
        short2 dxy = hw[k];
        float b = bf2f(relhq[dxy.x]) + bf2f(relwq[dxy.y]);
        float sv = fmaf(st[reg], 0.125f, b);
        float e = __expf(sv);
        if (nt == 6) {
          if (reg >= 4) e = 0.f;
          else if (hb) e = 0.f;
        }
        pv[reg] = e;
        lsum += e;
      }
      psum += lsum;
      unsigned pk[8], xk[8];
#pragma unroll
      for (int i = 0; i < 8; ++i) pk[i] = pack2(pv[2 * i], pv[2 * i + 1]);
#pragma unroll
      for (int i = 0; i < 8; ++i) xk[i] = (unsigned)__shfl_xor((int)pk[i], 32);

      {
        bfv8 pf = mkfrag(hb ? xk[2] : pk[0], hb ? xk[3] : pk[1],
                         hb ? pk[2] : xk[0], hb ? pk[3] : xk[1]);
        int kb = nt * 32 + hb * 8;
        if (nt == 6 && hb) kb = 0;
        oacc0 = MFMA32(pf, *(const bfv8*)&Vt[l31 * 204 + kb], oacc0);
        oacc1 = MFMA32(pf, *(const bfv8*)&Vt[(32 + l31) * 204 + kb], oacc1);
      }
      {
        bfv8 pf = mkfrag(hb ? xk[6] : pk[4], hb ? xk[7] : pk[5],
                         hb ? pk[6] : xk[4], hb ? pk[7] : xk[5]);
        int kb = nt * 32 + 16 + hb * 8;
        if (nt == 6) kb = 0;
        oacc0 = MFMA32(pf, *(const bfv8*)&Vt[l31 * 204 + kb], oacc0);
        oacc1 = MFMA32(pf, *(const bfv8*)&Vt[(32 + l31) * 204 + kb], oacc1);
      }
    }

    float inv = 1.f / (psum + __shfl_xor(psum, 32));
    short* AOr = AO + (wdx * 196) * 768 + head * 64;
#pragma unroll
    for (int reg = 0; reg < 16; ++reg) {
      int qoff = (reg & 3) + 8 * (reg >> 2) + 4 * hb;
      float invr = __shfl(inv, qoff);
      int q = m0 + qoff;
      if (q < 196) {
        AOr[q * 768 + l31] = f2bf(oacc0[reg] * invr);
        AOr[q * 768 + 32 + l31] = f2bf(oacc1[reg] * invr);
      }
    }
  }
}

// ------------------------------------------------------------- launch
extern "C" void kernel_launch(void* const* d_in, const int* in_sizes, int n_in,
                              void* d_out, int out_size, void* d_ws, size_t ws_size,
                              hipStream_t stream) {
  const float* x = (const float*)d_in[0];
  const float* qkv_w = (const float*)d_in[1];
  const float* qkv_b = (const float*)d_in[2];
  const float* proj_w = (const float*)d_in[3];
  const float* proj_b = (const float*)d_in[4];
  const float* rph = (const float*)d_in[5];
  const float* rpw = (const float*)d_in[6];
  float* out = (float*)d_out;

  char* ws = (char*)d_ws;
  short* Q  = (short*)(ws);
  short* K  = (short*)(ws + 77070336);
  short* V  = (short*)(ws + 154140672);
  short* AO = (short*)(ws + 231211008);
  short* Wq = (short*)(ws + 308281344);
  short* Wp = (short*)(ws + 311820288);
  // d_out doubles as scratch until proj_gemm overwrites it completely
  short* Xbf = (short*)d_out;
  short* Rhb = (short*)((char*)d_out + 77070336);
  short* Rwb = Rhb + 2048;

  hipLaunchKernelGGL(convert_all, dim3(39940), dim3(256), 0, stream,
                     x, qkv_w, proj_w, rph, rpw, Xbf, Wq, Wp, Rhb, Rwb);
  hipLaunchKernelGGL(qkv_gemm, dim3(1764), dim3(512), 0, stream,
                     Xbf, Wq, qkv_b, Q, K, V);
  hipLaunchKernelGGL(attn_kernel, dim3(3072), dim3(256), 0, stream,
                     Q, K, V, Rhb, Rwb, AO);
  hipLaunchKernelGGL(proj_gemm, dim3(588), dim3(512), 0, stream,
                     AO, Wp, proj_b, out);
}

// Round 11
// 458.657 us; speedup vs baseline: 2.2810x; 2.2810x over previous
//
#include <hip/hip_runtime.h>
#include <stdint.h>

typedef __bf16 bfv8 __attribute__((ext_vector_type(8)));
typedef short s16x8 __attribute__((ext_vector_type(8)));
typedef short s16x4 __attribute__((ext_vector_type(4)));
typedef float f32x4 __attribute__((ext_vector_type(4)));
typedef float f32x16 __attribute__((ext_vector_type(16)));

#define MFMA(a, b, c) __builtin_amdgcn_mfma_f32_16x16x32_bf16(a, b, c, 0, 0, 0)
#define MFMA32(a, b, c) __builtin_amdgcn_mfma_f32_32x32x16_bf16(a, b, c, 0, 0, 0)

__device__ __forceinline__ short f2bf(float f) {
  union { float f; unsigned u; } v; v.f = f;
  unsigned r = v.u + 0x7FFFu + ((v.u >> 16) & 1u);
  return (short)(r >> 16);
}
__device__ __forceinline__ float bf2f(short s) {
  union { unsigned u; float f; } v; v.u = ((unsigned)(unsigned short)s) << 16;
  return v.f;
}
__device__ __forceinline__ unsigned pack2(float a, float b) {
  return (unsigned)(unsigned short)f2bf(a) | ((unsigned)(unsigned short)f2bf(b) << 16);
}
__device__ __forceinline__ bfv8 mkfrag(unsigned a, unsigned b, unsigned c, unsigned d) {
  union { unsigned u[4]; bfv8 v; } t; t.u[0] = a; t.u[1] = b; t.u[2] = c; t.u[3] = d;
  return t.v;
}

// async global->LDS, 16B per lane; lds base must be wave-uniform
__device__ __forceinline__ void async_cp16(const short* g, short* l) {
  auto gp = reinterpret_cast<const uint32_t __attribute__((address_space(1)))*>(
      reinterpret_cast<uintptr_t>(g));
  auto lp = reinterpret_cast<uint32_t __attribute__((address_space(3)))*>(
      reinterpret_cast<uintptr_t>(l));
  __builtin_amdgcn_global_load_lds(gp, lp, 16, 0, 0);
}

// ------------------------------------------------------------- convert pass
__global__ __launch_bounds__(256) void convert_all(
    const float* __restrict__ x, const float* __restrict__ qkvw,
    const float* __restrict__ projw, const float* __restrict__ rph,
    const float* __restrict__ rpw, short* __restrict__ Xbf,
    short* __restrict__ Wq, short* __restrict__ Wp, short* __restrict__ Rhb,
    short* __restrict__ Rwb) {
  const int NX = 9633792;   // 50176*192
  const int NW1 = 442368;   // 2304*768/4
  const int NW2 = 147456;   // 768*768/4
  const int NR = 512;       // 32*16
  int idx = blockIdx.x * 256 + threadIdx.x;
  if (idx < NX) {
    int t = idx / 192, cq = idx - t * 192;
    int wdx = t / 196, n = t - wdx * 196;
    int b = wdx >> 4, wl = wdx & 15;
    int nh = n / 14;
    int hh = (wl >> 2) * 14 + nh;
    int ww = (wl & 3) * 14 + (n - nh * 14);
    float4 v = *(const float4*)(x + ((b * 56 + hh) * 56 + ww) * 768 + cq * 4);
    s16x4 s = {f2bf(v.x), f2bf(v.y), f2bf(v.z), f2bf(v.w)};
    *(s16x4*)(Xbf + idx * 4) = s;
  } else if (idx < NX + NW1) {
    int i = idx - NX;
    float4 v = ((const float4*)qkvw)[i];
    s16x4 s = {f2bf(v.x), f2bf(v.y), f2bf(v.z), f2bf(v.w)};
    *(s16x4*)(Wq + i * 4) = s;
  } else if (idx < NX + NW1 + NW2) {
    int i = idx - NX - NW1;
    float4 v = ((const float4*)projw)[i];
    s16x4 s = {f2bf(v.x), f2bf(v.y), f2bf(v.z), f2bf(v.w)};
    *(s16x4*)(Wp + i * 4) = s;
  } else if (idx < NX + NW1 + NW2 + 2 * NR) {
    int i = idx - NX - NW1 - NW2;
    int which = i >> 9;
    int j = i & 511;
    int p = j >> 4, q = j & 15;
    const float* src = which ? rpw : rph;
    short* dst = which ? Rwb : Rhb;
    s16x4 s = {0, 0, 0, 0};
    if (p < 27) {
      float4 v = *(const float4*)(src + p * 64 + q * 4);
      s = (s16x4){f2bf(v.x), f2bf(v.y), f2bf(v.z), f2bf(v.w)};
    }
    *(s16x4*)(dst + p * 64 + q * 4) = s;
  }
}

// ============================================================= 256^2 GEMMs
// R4 structure (verified 215.7us qkv): BM=BN=256, BK=64, 512 thr (8 waves
// 2x4), per-wave 128x64 out. LDS 2 bufs x (A+B) = 128 KB. Stage(t+1) issued
// before COMPUTE(t); vmcnt(0)+raw barrier per half-tile. Swizzle: source
// chunk ss = ls^lr pre-swizzle, linear LDS; read slot = (kh*4+g)^(li&7)
// -> 2-way conflicts only (free).

#define GEMM_PRE()                                                            \
  const int tid = threadIdx.x, lane = tid & 63, w = tid >> 6;                 \
  const int wr = w >> 2, wc = w & 3;                                          \
  const int li = lane & 15, g = lane >> 4;                                    \
  const int lr = lane >> 3, ls = lane & 7;                                    \
  const int ss = ls ^ lr;                                                     \
  f32x4 acc[8][4];                                                            \
  _Pragma("unroll") for (int i = 0; i < 8; ++i)                               \
  _Pragma("unroll") for (int j = 0; j < 4; ++j)                               \
      acc[i][j] = (f32x4){0.f, 0.f, 0.f, 0.f};

#define GEMM_STAGE(buf, t)                                                    \
  {                                                                           \
    _Pragma("unroll") for (int q = 0; q < 4; ++q) {                           \
      async_cp16(Asrc + q * 8 * 768 + (t) * 64, &As[buf][(w * 32 + q * 8) * 64]); \
      async_cp16(Bsrc + q * 8 * 768 + (t) * 64, &Bs[buf][(w * 32 + q * 8) * 64]); \
    }                                                                         \
  }

#define GEMM_WAITBAR()                                                        \
  asm volatile("s_waitcnt vmcnt(0)" ::: "memory");                            \
  __builtin_amdgcn_sched_barrier(0);                                          \
  __builtin_amdgcn_s_barrier();

#define GEMM_COMPUTE(buf)                                                     \
  {                                                                           \
    const short* Ab = As[buf];                                                \
    const short* Bb = Bs[buf];                                                \
    bfv8 bfr[4][2];                                                           \
    _Pragma("unroll") for (int nf = 0; nf < 4; ++nf)                          \
    _Pragma("unroll") for (int kh = 0; kh < 2; ++kh)                          \
        bfr[nf][kh] = *(const bfv8*)&Bb[(wc * 64 + nf * 16 + li) * 64 +       \
                                        (((kh * 4 + g) ^ (li & 7)) * 8)];     \
    _Pragma("unroll") for (int mh = 0; mh < 2; ++mh) {                        \
      bfv8 af[4][2];                                                          \
      _Pragma("unroll") for (int mf = 0; mf < 4; ++mf)                        \
      _Pragma("unroll") for (int kh = 0; kh < 2; ++kh)                        \
          af[mf][kh] = *(const bfv8*)&Ab[(wr * 128 + mh * 64 + mf * 16 + li) * 64 + \
                                         (((kh * 4 + g) ^ (li & 7)) * 8)];    \
      __builtin_amdgcn_s_setprio(1);                                          \
      _Pragma("unroll") for (int mf = 0; mf < 4; ++mf)                        \
      _Pragma("unroll") for (int nf = 0; nf < 4; ++nf) {                      \
        acc[mh * 4 + mf][nf] = MFMA(af[mf][0], bfr[nf][0], acc[mh * 4 + mf][nf]); \
        acc[mh * 4 + mf][nf] = MFMA(af[mf][1], bfr[nf][1], acc[mh * 4 + mf][nf]); \
      }                                                                       \
      __builtin_amdgcn_s_setprio(0);                                          \
    }                                                                         \
  }

#define GEMM_LOOP()                                                           \
  GEMM_STAGE(0, 0);                                                           \
  _Pragma("unroll 1") for (int tt = 0; tt < 6; ++tt) {                        \
    GEMM_WAITBAR();                                                           \
    GEMM_STAGE(1, 2 * tt + 1);                                                \
    GEMM_COMPUTE(0);                                                          \
    GEMM_WAITBAR();                                                           \
    if (tt < 5) GEMM_STAGE(0, 2 * tt + 2);                                    \
    GEMM_COMPUTE(1);                                                          \
  }

// ------------------------------------------------------------- qkv gemm
__global__ __launch_bounds__(512, 2) void qkv_gemm(
    const short* __restrict__ Xbf, const short* __restrict__ Wq,
    const float* __restrict__ qkvb, short* __restrict__ Q,
    short* __restrict__ K, short* __restrict__ V) {
  __shared__ short As[2][256 * 64];
  __shared__ short Bs[2][256 * 64];
  // grid 1764 = 196 m-tiles x 9 n-tiles; bijective XCD swizzle (q=220, r=4)
  int bid = blockIdx.x;
  int xcd = bid & 7, pos = bid >> 3;
  int wgid = (xcd < 4) ? xcd * 221 + pos : 884 + (xcd - 4) * 220 + pos;
  int bm = wgid / 9, bn = wgid - bm * 9;

  GEMM_PRE();
  const short* Asrc = Xbf + (bm * 256 + w * 32 + lr) * 768 + ss * 8;
  const short* Bsrc = Wq + (bn * 256 + w * 32 + lr) * 768 + ss * 8;

  GEMM_LOOP();

  // epilogue: scatter into Q/K/V [window*head][196][64]
  short* dst = (bn < 3) ? Q : ((bn < 6) ? K : V);
  const int head = (bn % 3) * 4 + wc;
  float bias[4];
#pragma unroll
  for (int nf = 0; nf < 4; ++nf) bias[nf] = qkvb[bn * 256 + wc * 64 + nf * 16 + li];
#pragma unroll
  for (int mi = 0; mi < 8; ++mi) {
    int rbase = bm * 256 + wr * 128 + (mi >> 2) * 64 + (mi & 3) * 16 + g * 4;
#pragma unroll
    for (int j = 0; j < 4; ++j) {
      int trow = rbase + j;
      int wdx = trow / 196, n = trow - wdx * 196;
      int base = ((wdx * 12 + head) * 196 + n) * 64;
#pragma unroll
      for (int nf = 0; nf < 4; ++nf)
        dst[base + nf * 16 + li] = f2bf(acc[mi][nf][j] + bias[nf]);
    }
  }
}

// ------------------------------------------------------------- proj gemm
__global__ __launch_bounds__(512, 2) void proj_gemm(
    const short* __restrict__ AO, const short* __restrict__ Wp,
    const float* __restrict__ projb, float* __restrict__ out) {
  __shared__ short As[2][256 * 64];
  __shared__ short Bs[2][256 * 64];
  // grid 588 = 196 x 3; bijective XCD swizzle (q=73, r=4)
  int bid = blockIdx.x;
  int xcd = bid & 7, pos = bid >> 3;
  int wgid = (xcd < 4) ? xcd * 74 + pos : 296 + (xcd - 4) * 73 + pos;
  int bm = wgid / 3, bn = wgid - bm * 3;

  GEMM_PRE();
  const short* Asrc = AO + (bm * 256 + w * 32 + lr) * 768 + ss * 8;
  const short* Bsrc = Wp + (bn * 256 + w * 32 + lr) * 768 + ss * 8;

  GEMM_LOOP();

  // epilogue: window-unpartition scatter, f32 out
  float bias[4];
#pragma unroll
  for (int nf = 0; nf < 4; ++nf) bias[nf] = projb[bn * 256 + wc * 64 + nf * 16 + li];
  const int col0 = bn * 256 + wc * 64 + li;
#pragma unroll
  for (int mi = 0; mi < 8; ++mi) {
    int rbase = bm * 256 + wr * 128 + (mi >> 2) * 64 + (mi & 3) * 16 + g * 4;
#pragma unroll
    for (int j = 0; j < 4; ++j) {
      int trow = rbase + j;
      int wdx = trow / 196, n = trow - wdx * 196;
      int b = wdx >> 4, wl = wdx & 15;
      int nh = n / 14;
      int hh = (wl >> 2) * 14 + nh;
      int ww = (wl & 3) * 14 + (n - nh * 14);
      float* orow = out + ((b * 56 + hh) * 56 + ww) * 768 + col0;
#pragma unroll
      for (int nf = 0; nf < 4; ++nf)
        orow[nf * 16] = acc[mi][nf][j] + bias[nf];
    }
  }
}

// ------------------------------------------------------------- attention
// R3/R9-proven 512-thread version (1 block/CU; VGPR is the binding
// constraint, so no occupancy tricks). One block per (window, head); 8
// waves; 32x32x16 MFMA, swapped QK^T, in-register P exchange (no P LDS),
// no-max softmax, K staged in LDS with XOR swizzle. R10's bijective
// XCD-aligned bh mapping kept (windows 0..31 -> XCD0, matches qkv writes).
__global__ __launch_bounds__(512, 4) void attn_kernel(
    const short* __restrict__ Q, const short* __restrict__ K,
    const short* __restrict__ V, const short* __restrict__ Rhb,
    const short* __restrict__ Rwb, short* __restrict__ AO) {
  __shared__ short Ks[196 * 64];    // K rows, 16B-chunk XOR swizzle
  __shared__ short Vt[64 * 204];    // V^T [d][k], k 0..203 (196.. zeroed)
  __shared__ short relh[224 * 28];  // relall_h[q][p]
  __shared__ short relw[224 * 28];
  __shared__ short2 hw[224];        // (13-hk, 13-wk) per k

  const int bid = blockIdx.x;
  const int bh = (bid & 7) * 384 + (bid >> 3);  // 3072 = 8*384, bijective
  const int wdx = bh / 12, head = bh - wdx * 12;
  const int tid = threadIdx.x, lane = tid & 63, wave = tid >> 6;
  const int l31 = lane & 31, hb = lane >> 5;
  const short* Qb = Q + bh * 12544;
  const short* Kb = K + bh * 12544;
  const short* Vb = V + bh * 12544;

  const int m0 = wave * 32;
  const int qv = (m0 + l31 > 195) ? 195 : m0 + l31;

  // ---- per-wave: Q fragments + rel mini-GEMMs (waves 0..6) ----
  bfv8 qf[4];
  if (wave < 7) {
    f32x16 ra = {0.f, 0.f, 0.f, 0.f, 0.f, 0.f, 0.f, 0.f,
                 0.f, 0.f, 0.f, 0.f, 0.f, 0.f, 0.f, 0.f};
    f32x16 rw_ = ra;
#pragma unroll
    for (int s = 0; s < 4; ++s) {
      qf[s] = *(const bfv8*)(Qb + qv * 64 + s * 16 + hb * 8);
      ra = MFMA32(*(const bfv8*)(Rhb + l31 * 64 + s * 16 + hb * 8), qf[s], ra);
      rw_ = MFMA32(*(const bfv8*)(Rwb + l31 * 64 + s * 16 + hb * 8), qf[s], rw_);
    }
#pragma unroll
    for (int reg = 0; reg < 16; ++reg) {
      int p = (reg & 3) + 8 * (reg >> 2) + 4 * hb;
      if (!(hb && reg >= 12)) {  // p < 28
        relh[(m0 + l31) * 28 + p] = f2bf(ra[reg]);
        relw[(m0 + l31) * 28 + p] = f2bf(rw_[reg]);
      }
    }
  }

  // ---- staging (all 8 waves) ----
  if (tid < 64) {
    s16x8 z = {0, 0, 0, 0, 0, 0, 0, 0};
    *(s16x8*)&Vt[tid * 204 + 196] = z;
  }
  for (int c = tid; c < 1568; c += 512) {
    int r = c >> 3, cc = c & 7;
    s16x8 v = *(const s16x8*)(Kb + r * 64 + cc * 8);
    *(s16x8*)&Ks[r * 64 + (((cc ^ (r & 7))) << 3)] = v;
  }
  for (int t = tid; t < 784; t += 512) {
    int dseg = t / 98, kp = t - dseg * 98, d0 = dseg * 8;
    s16x8 a = *(const s16x8*)(Vb + (2 * kp) * 64 + d0);
    s16x8 b = *(const s16x8*)(Vb + (2 * kp + 1) * 64 + d0);
#pragma unroll
    for (int i = 0; i < 8; ++i)
      *(short2*)&Vt[(d0 + i) * 204 + 2 * kp] = make_short2(a[i], b[i]);
  }
  if (tid < 224) {
    int kc = (tid > 195) ? 195 : tid;
    int hk = kc / 14, wk = kc - hk * 14;
    hw[tid] = make_short2((short)(13 - hk), (short)(13 - wk));
  }
  __syncthreads();

  if (wave >= 7) return;

  const int hq = qv / 14;
  const int wq = qv - hq * 14;
  const short* relhq = &relh[qv * 28 + hq];
  const short* relwq = &relw[qv * 28 + wq];

  f32x16 oacc0 = {0.f, 0.f, 0.f, 0.f, 0.f, 0.f, 0.f, 0.f,
                  0.f, 0.f, 0.f, 0.f, 0.f, 0.f, 0.f, 0.f};
  f32x16 oacc1 = oacc0;
  float psum = 0.f;

#pragma unroll
  for (int nt = 0; nt < 7; ++nt) {
    int krow = nt * 32 + l31;
    int krc = (krow > 195) ? 195 : krow;
    const int rb = krc * 64, rx = krc & 7;
    f32x16 st = {0.f, 0.f, 0.f, 0.f, 0.f, 0.f, 0.f, 0.f,
                 0.f, 0.f, 0.f, 0.f, 0.f, 0.f, 0.f, 0.f};
#pragma unroll
    for (int s = 0; s < 4; ++s) {
      bfv8 kf = *(const bfv8*)&Ks[rb + (((2 * s + hb) ^ rx) << 3)];
      st = MFMA32(kf, qf[s], st);
    }
    float pv[16];
    float lsum = 0.f;
#pragma unroll
    for (int reg = 0; reg < 16; ++reg) {
      int koff = (reg & 3) + 8 * (reg >> 2) + 4 * hb;
      int k = nt * 32 + koff;
      short2 dxy = hw[k];
      float b = bf2f(relhq[dxy.x]) + bf2f(relwq[dxy.y]);
      float sv = fmaf(st[reg], 0.125f, b);
      float e = __expf(sv);
      if (nt == 6) {
        if (reg >= 4) e = 0.f;
        else if (hb) e = 0.f;
      }
      pv[reg] = e;
      lsum += e;
    }
    psum += lsum;
    unsigned pk[8], xk[8];
#pragma unroll
    for (int i = 0; i < 8; ++i) pk[i] = pack2(pv[2 * i], pv[2 * i + 1]);
#pragma unroll
    for (int i = 0; i < 8; ++i) xk[i] = (unsigned)__shfl_xor((int)pk[i], 32);

    {
      bfv8 pf = mkfrag(hb ? xk[2] : pk[0], hb ? xk[3] : pk[1],
                       hb ? pk[2] : xk[0], hb ? pk[3] : xk[1]);
      int kb = nt * 32 + hb * 8;
      if (nt == 6 && hb) kb = 0;
      oacc0 = MFMA32(pf, *(const bfv8*)&Vt[l31 * 204 + kb], oacc0);
      oacc1 = MFMA32(pf, *(const bfv8*)&Vt[(32 + l31) * 204 + kb], oacc1);
    }
    {
      bfv8 pf = mkfrag(hb ? xk[6] : pk[4], hb ? xk[7] : pk[5],
                       hb ? pk[6] : xk[4], hb ? pk[7] : xk[5]);
      int kb = nt * 32 + 16 + hb * 8;
      if (nt == 6) kb = 0;
      oacc0 = MFMA32(pf, *(const bfv8*)&Vt[l31 * 204 + kb], oacc0);
      oacc1 = MFMA32(pf, *(const bfv8*)&Vt[(32 + l31) * 204 + kb], oacc1);
    }
  }

  float inv = 1.f / (psum + __shfl_xor(psum, 32));
  short* AOr = AO + (wdx * 196) * 768 + head * 64;
#pragma unroll
  for (int reg = 0; reg < 16; ++reg) {
    int qoff = (reg & 3) + 8 * (reg >> 2) + 4 * hb;
    float invr = __shfl(inv, qoff);
    int q = m0 + qoff;
    if (q < 196) {
      AOr[q * 768 + l31] = f2bf(oacc0[reg] * invr);
      AOr[q * 768 + 32 + l31] = f2bf(oacc1[reg] * invr);
    }
  }
}

// ------------------------------------------------------------- launch
extern "C" void kernel_launch(void* const* d_in, const int* in_sizes, int n_in,
                              void* d_out, int out_size, void* d_ws, size_t ws_size,
                              hipStream_t stream) {
  const float* x = (const float*)d_in[0];
  const float* qkv_w = (const float*)d_in[1];
  const float* qkv_b = (const float*)d_in[2];
  const float* proj_w = (const float*)d_in[3];
  const float* proj_b = (const float*)d_in[4];
  const float* rph = (const float*)d_in[5];
  const float* rpw = (const float*)d_in[6];
  float* out = (float*)d_out;

  char* ws = (char*)d_ws;
  short* Q  = (short*)(ws);
  short* K  = (short*)(ws + 77070336);
  short* V  = (short*)(ws + 154140672);
  short* AO = (short*)(ws + 231211008);
  short* Wq = (short*)(ws + 308281344);
  short* Wp = (short*)(ws + 311820288);
  // d_out doubles as scratch until proj_gemm overwrites it completely
  short* Xbf = (short*)d_out;
  short* Rhb = (short*)((char*)d_out + 77070336);
  short* Rwb = Rhb + 2048;

  hipLaunchKernelGGL(convert_all, dim3(39940), dim3(256), 0, stream,
                     x, qkv_w, proj_w, rph, rpw, Xbf, Wq, Wp, Rhb, Rwb);
  hipLaunchKernelGGL(qkv_gemm, dim3(1764), dim3(512), 0, stream,
                     Xbf, Wq, qkv_b, Q, K, V);
  hipLaunchKernelGGL(attn_kernel, dim3(3072), dim3(512), 0, stream,
                     Q, K, V, Rhb, Rwb, AO);
  hipLaunchKernelGGL(proj_gemm, dim3(588), dim3(512), 0, stream,
                     AO, Wp, proj_b, out);
}